// Round 14
// baseline (540.636 us; speedup 1.0000x reference)
//
#include <hip/hip_runtime.h>
#include <hip/hip_bf16.h>
#include <math.h>

#define NW 2   // waves (=samples) per 128-thread block

typedef __attribute__((ext_vector_type(8)))  short bf16x8;
typedef __attribute__((ext_vector_type(16))) float f32x16;

__device__ __forceinline__ float bperm(int srcidx, float x) {
    return __int_as_float(__builtin_amdgcn_ds_bpermute(srcidx, __float_as_int(x)));
}
// f32 -> bf16 bits, RNE (manual, bit-deterministic: probes)
__device__ __forceinline__ unsigned f2bfu(float x) {
    unsigned u = __float_as_uint(x);
    return (u + 0x7fffu + ((u >> 16) & 1u)) >> 16;
}
__device__ __forceinline__ float bf2f(unsigned hb) { return __uint_as_float(hb << 16); }
__device__ __forceinline__ unsigned short bfb(float x) {
    __hip_bfloat16 b = __float2bfloat16(x);
    unsigned short u;
    __builtin_memcpy(&u, &b, sizeof(u));
    return u;
}
__device__ __forceinline__ void split(float x, unsigned short& hb, unsigned short& lb) {
    hb = bfb(x);
    float lo = x - bf2f(hb);
    lb = bfb(lo);
}
template <int JM>
__device__ __forceinline__ bf16x8 pick(const unsigned short (&s)[8]) {
    bf16x8 r;
    #pragma unroll
    for (int j = 0; j < 8; ++j) {
        int idx = (JM == 0) ? j : (JM == 1 ? (j ^ 4) : (7 - j));
        r[j] = (short)s[idx];
    }
    return r;
}

// logm via deg-12 Chebyshev of log on [1,8]; MFMA 32x32x16 bf16 hi/lo split;
// layout discovered by 3 one-MFMA probes (proven R10-R12, absmax 0.0).
// R13: BOTH phases (yhat,y) fused in one pass — two independent MFMA/recurrence
// chains interleave, hiding per-STEP dependency latency (R12 was latency-bound
// at 1 wave/SIMD).
__global__ __launch_bounds__(128, 2)
void geo_loss_mfma(const float* __restrict__ yhat, const float* __restrict__ y,
                   float* __restrict__ out, int B)
{
    __shared__ unsigned short hA[NW][32][40], lA[NW][32][40];  // phase-A T_k planes
    __shared__ unsigned short hBp[NW][32][40], lBp[NW][32][40];// phase-B T_k planes
    __shared__ float bl[NW];

    const int t    = threadIdx.x;
    const int w    = t >> 6;
    const int lane = t & 63;
    const int c    = lane & 31;
    const int h    = lane >> 5;

    int b = blockIdx.x * NW + w;
    const float valid = (b < B) ? 1.f : 0.f;
    if (b >= B) b = B - 1;

    const f32x16 zz = {0.f,0.f,0.f,0.f,0.f,0.f,0.f,0.f,0.f,0.f,0.f,0.f,0.f,0.f,0.f,0.f};
    float sent = 0.f;

    // ---- probe 1: relative A/B slot-labeling delta (6 hypotheses) ----
    bf16x8 pa;
    #pragma unroll
    for (int j = 0; j < 8; ++j) pa[j] = (short)f2bfu((float)(8*h + j + 1));
    int sel = -1;
    #pragma unroll
    for (int cand = 0; cand < 6; ++cand) {
        const int hfc = cand & 1, jmc = cand >> 1;
        bf16x8 pb;
        #pragma unroll
        for (int j = 0; j < 8; ++j) {
            int hh = hfc ? (1 - h) : h;
            int jj = (jmc == 0) ? j : (jmc == 1 ? (j ^ 4) : (7 - j));
            float lab = (float)(8*hh + jj + 1);
            pb[j] = (short)f2bfu(lab * lab);
        }
        f32x16 pr = __builtin_amdgcn_mfma_f32_32x32x16_bf16(pa, pb, zz, 0, 0, 0);
        if (sel < 0 && __ballot(pr[0] != 18496.f) == 0ull) sel = cand;
    }
    if (sel < 0) { sent += 1.0e10f; sel = 0; }
    const int hf = sel & 1, jm = sel >> 1;

    // ---- probe 2: C (lane,reg) -> row map ----
    bf16x8 pa2, pb1;
    #pragma unroll
    for (int j = 0; j < 8; ++j) {
        pa2[j] = (short)f2bfu((float)(c + 1));
        pb1[j] = (short)f2bfu(1.f);
    }
    f32x16 r2 = __builtin_amdgcn_mfma_f32_32x32x16_bf16(pa2, pb1, zz, 0, 0, 0);
    int rws[16]; bool ok2 = true;
    #pragma unroll
    for (int i = 0; i < 16; ++i) {
        float q = r2[i] * 0.0625f;
        int ri = (int)(q + 0.5f);
        ok2 = ok2 && (fabsf(q - (float)ri) < 1e-3f) && ri >= 1 && ri <= 32;
        rws[i] = ri - 1;
    }
    if (__ballot(!ok2) != 0ull) {
        sent += 2.0e10f;
        #pragma unroll
        for (int i = 0; i < 16; ++i) rws[i] = (i & 3) + 8*(i >> 2) + 4*h;
    }

    // ---- probe 3: C lane -> col map ----
    f32x16 r3 = __builtin_amdgcn_mfma_f32_32x32x16_bf16(pb1, pa2, zz, 0, 0, 0);
    int colstar;
    {
        float q = r3[0] * 0.0625f;
        int ci = (int)(q + 0.5f);
        bool ok3 = (fabsf(q - (float)ci) < 1e-3f) && ci >= 1 && ci <= 32;
        colstar = ci - 1;
        if (__ballot(!ok3) != 0ull) { sent += 4.0e10f; colstar = c; }
    }
    if (lane == 0 && sent > 0.f) atomicAdd(out, sent);

    bool qok = true;
    #pragma unroll
    for (int q = 0; q < 4; ++q)
        qok = qok && ((rws[4*q] & 3) == 0) && (rws[4*q+1] == rws[4*q]+1)
                  && (rws[4*q+2] == rws[4*q]+2) && (rws[4*q+3] == rws[4*q]+3);
    const bool allQuad = (__ballot(!qok) == 0ull);

    const float INV = 0.2857142857142857f;   // 1/3.5
    const int abase = 8 * (h ^ hf);

    auto packw = [](const unsigned short (&s)[8]) {
        return make_uint4((unsigned)s[0] | ((unsigned)s[1] << 16),
                          (unsigned)s[2] | ((unsigned)s[3] << 16),
                          (unsigned)s[4] | ((unsigned)s[5] << 16),
                          (unsigned)s[6] | ((unsigned)s[7] << 16));
    };

    // ---- load + stage both phases; build A-frags ----
    bf16x8 A1h0, A1l0, A1h1, A1l1, A2h0, A2l0, A2h1, A2l1;
    {
        const float* Mp = yhat + ((size_t)b << 10);
        unsigned short H0[8], L0[8], H1[8], L1[8];
        const float4* p0 = reinterpret_cast<const float4*>(Mp + c*32 + abase);
        float4 q0 = p0[0], q1 = p0[1];
        float f0[8] = {q0.x,q0.y,q0.z,q0.w, q1.x,q1.y,q1.z,q1.w};
        const float4* p1 = reinterpret_cast<const float4*>(Mp + c*32 + 16 + abase);
        float4 q2 = p1[0], q3 = p1[1];
        float f1[8] = {q2.x,q2.y,q2.z,q2.w, q3.x,q3.y,q3.z,q3.w};
        #pragma unroll
        for (int m = 0; m < 8; ++m) {
            int k0 = abase + m, k1 = 16 + abase + m;
            float x0 = (f0[m] - ((k0 == c) ? 4.5f : 0.f)) * INV;
            float x1 = (f1[m] - ((k1 == c) ? 4.5f : 0.f)) * INV;
            split(x0, H0[m], L0[m]);
            split(x1, H1[m], L1[m]);
        }
        *reinterpret_cast<uint4*>(&hA[w][c][abase])      = packw(H0);
        *reinterpret_cast<uint4*>(&lA[w][c][abase])      = packw(L0);
        *reinterpret_cast<uint4*>(&hA[w][c][16 + abase]) = packw(H1);
        *reinterpret_cast<uint4*>(&lA[w][c][16 + abase]) = packw(L1);
        if (jm == 0)      { A1h0=pick<0>(H0); A1l0=pick<0>(L0); A1h1=pick<0>(H1); A1l1=pick<0>(L1); }
        else if (jm == 1) { A1h0=pick<1>(H0); A1l0=pick<1>(L0); A1h1=pick<1>(H1); A1l1=pick<1>(L1); }
        else              { A1h0=pick<2>(H0); A1l0=pick<2>(L0); A1h1=pick<2>(H1); A1l1=pick<2>(L1); }
    }
    {
        const float* Mp = y + ((size_t)b << 10);
        unsigned short H0[8], L0[8], H1[8], L1[8];
        const float4* p0 = reinterpret_cast<const float4*>(Mp + c*32 + abase);
        float4 q0 = p0[0], q1 = p0[1];
        float f0[8] = {q0.x,q0.y,q0.z,q0.w, q1.x,q1.y,q1.z,q1.w};
        const float4* p1 = reinterpret_cast<const float4*>(Mp + c*32 + 16 + abase);
        float4 q2 = p1[0], q3 = p1[1];
        float f1[8] = {q2.x,q2.y,q2.z,q2.w, q3.x,q3.y,q3.z,q3.w};
        #pragma unroll
        for (int m = 0; m < 8; ++m) {
            int k0 = abase + m, k1 = 16 + abase + m;
            float x0 = (f0[m] - ((k0 == c) ? 4.5f : 0.f)) * INV;
            float x1 = (f1[m] - ((k1 == c) ? 4.5f : 0.f)) * INV;
            split(x0, H0[m], L0[m]);
            split(x1, H1[m], L1[m]);
        }
        *reinterpret_cast<uint4*>(&hBp[w][c][abase])      = packw(H0);
        *reinterpret_cast<uint4*>(&lBp[w][c][abase])      = packw(L0);
        *reinterpret_cast<uint4*>(&hBp[w][c][16 + abase]) = packw(H1);
        *reinterpret_cast<uint4*>(&lBp[w][c][16 + abase]) = packw(L1);
        if (jm == 0)      { A2h0=pick<0>(H0); A2l0=pick<0>(L0); A2h1=pick<0>(H1); A2l1=pick<0>(L1); }
        else if (jm == 1) { A2h0=pick<1>(H0); A2l0=pick<1>(L0); A2h1=pick<1>(H1); A2l1=pick<1>(L1); }
        else              { A2h0=pick<2>(H0); A2l0=pick<2>(L0); A2h1=pick<2>(H1); A2l1=pick<2>(L1); }
    }

    // ---- init recurrence state for both chains ----
    float U1[16], V1[16], P1[16], U2[16], V2[16], P2[16];
    #pragma unroll
    for (int i = 0; i < 16; ++i) {
        float dg = (rws[i] == colstar) ? 1.f : 0.f;
        float tv1 = bf2f(hA[w][colstar][rws[i]])  + bf2f(lA[w][colstar][rws[i]]);
        float tv2 = bf2f(hBp[w][colstar][rws[i]]) + bf2f(lBp[w][colstar][rws[i]]);
        V1[i] = tv1; V2[i] = tv2; U1[i] = dg; U2[i] = dg;
        P1[i] = fmaf(0.95518452f, tv1, 1.2986135f * dg);
        P2[i] = fmaf(0.95518452f, tv2, 1.2986135f * dg);
    }

    // dual-chain Chebyshev step: the two 6-MFMA chains are independent -> ILP
    auto STEP = [&](float coef, float (&W1)[16], float (&W2)[16], bool dostore) {
        bf16x8 B1h0 = *reinterpret_cast<const bf16x8*>(&hA[w][c][8*h]);
        bf16x8 B1l0 = *reinterpret_cast<const bf16x8*>(&lA[w][c][8*h]);
        bf16x8 B1h1 = *reinterpret_cast<const bf16x8*>(&hA[w][c][16 + 8*h]);
        bf16x8 B1l1 = *reinterpret_cast<const bf16x8*>(&lA[w][c][16 + 8*h]);
        bf16x8 B2h0 = *reinterpret_cast<const bf16x8*>(&hBp[w][c][8*h]);
        bf16x8 B2l0 = *reinterpret_cast<const bf16x8*>(&lBp[w][c][8*h]);
        bf16x8 B2h1 = *reinterpret_cast<const bf16x8*>(&hBp[w][c][16 + 8*h]);
        bf16x8 B2l1 = *reinterpret_cast<const bf16x8*>(&lBp[w][c][16 + 8*h]);
        f32x16 a1 = zz, a2 = zz;
        a1 = __builtin_amdgcn_mfma_f32_32x32x16_bf16(A1h0, B1h0, a1, 0,0,0);
        a2 = __builtin_amdgcn_mfma_f32_32x32x16_bf16(A2h0, B2h0, a2, 0,0,0);
        a1 = __builtin_amdgcn_mfma_f32_32x32x16_bf16(A1h0, B1l0, a1, 0,0,0);
        a2 = __builtin_amdgcn_mfma_f32_32x32x16_bf16(A2h0, B2l0, a2, 0,0,0);
        a1 = __builtin_amdgcn_mfma_f32_32x32x16_bf16(A1l0, B1h0, a1, 0,0,0);
        a2 = __builtin_amdgcn_mfma_f32_32x32x16_bf16(A2l0, B2h0, a2, 0,0,0);
        a1 = __builtin_amdgcn_mfma_f32_32x32x16_bf16(A1h1, B1h1, a1, 0,0,0);
        a2 = __builtin_amdgcn_mfma_f32_32x32x16_bf16(A2h1, B2h1, a2, 0,0,0);
        a1 = __builtin_amdgcn_mfma_f32_32x32x16_bf16(A1h1, B1l1, a1, 0,0,0);
        a2 = __builtin_amdgcn_mfma_f32_32x32x16_bf16(A2h1, B2l1, a2, 0,0,0);
        a1 = __builtin_amdgcn_mfma_f32_32x32x16_bf16(A1l1, B1h1, a1, 0,0,0);
        a2 = __builtin_amdgcn_mfma_f32_32x32x16_bf16(A2l1, B2h1, a2, 0,0,0);
        #pragma unroll
        for (int i = 0; i < 16; ++i) {
            float n1 = fmaf(2.f, a1[i], -W1[i]);
            float n2 = fmaf(2.f, a2[i], -W2[i]);
            W1[i] = n1; W2[i] = n2;
            P1[i] = fmaf(coef, n1, P1[i]);
            P2[i] = fmaf(coef, n2, P2[i]);
        }
        if (dostore) {
            if (allQuad) {
                #pragma unroll
                for (int q = 0; q < 4; ++q) {
                    int rq = rws[4*q];
                    unsigned short h1[4], l1[4], h2[4], l2[4];
                    #pragma unroll
                    for (int e = 0; e < 4; ++e) {
                        split(W1[4*q+e], h1[e], l1[e]);
                        split(W2[4*q+e], h2[e], l2[e]);
                    }
                    *reinterpret_cast<uint2*>(&hA[w][colstar][rq]) =
                        make_uint2((unsigned)h1[0] | ((unsigned)h1[1] << 16),
                                   (unsigned)h1[2] | ((unsigned)h1[3] << 16));
                    *reinterpret_cast<uint2*>(&lA[w][colstar][rq]) =
                        make_uint2((unsigned)l1[0] | ((unsigned)l1[1] << 16),
                                   (unsigned)l1[2] | ((unsigned)l1[3] << 16));
                    *reinterpret_cast<uint2*>(&hBp[w][colstar][rq]) =
                        make_uint2((unsigned)h2[0] | ((unsigned)h2[1] << 16),
                                   (unsigned)h2[2] | ((unsigned)h2[3] << 16));
                    *reinterpret_cast<uint2*>(&lBp[w][colstar][rq]) =
                        make_uint2((unsigned)l2[0] | ((unsigned)l2[1] << 16),
                                   (unsigned)l2[2] | ((unsigned)l2[3] << 16));
                }
            } else {
                #pragma unroll
                for (int i = 0; i < 16; ++i) {
                    unsigned short hb, lb;
                    split(W1[i], hb, lb);
                    hA[w][colstar][rws[i]] = hb; lA[w][colstar][rws[i]] = lb;
                    split(W2[i], hb, lb);
                    hBp[w][colstar][rws[i]] = hb; lBp[w][colstar][rws[i]] = lb;
                }
            }
        }
    };

    STEP(-0.22809412f, U1, U2, true);    // T2
    STEP( 0.07262391f, V1, V2, true);    // T3
    STEP(-0.02601347f, U1, U2, true);    // T4
    STEP( 0.00993906f, V1, V2, true);    // T5
    STEP(-0.00395568f, U1, U2, true);    // T6
    STEP( 0.00161931f, V1, V2, true);    // T7
    STEP(-0.00067670f, U1, U2, true);    // T8
    STEP( 0.00028728f, V1, V2, true);    // T9
    STEP(-0.00012348f, U1, U2, true);    // T10
    STEP( 0.00005361f, V1, V2, true);    // T11
    STEP(-0.00002347f, U1, U2, false);   // T12

    float s = 0.f;
    #pragma unroll
    for (int i = 0; i < 16; ++i) { float d = P1[i] - P2[i]; s = fmaf(d, d, s); }
    #pragma unroll
    for (int m = 32; m >= 1; m >>= 1)
        s += bperm((lane ^ m) << 2, s);
    if (lane == 0) bl[w] = valid * sqrtf(fmaxf(s, 0.f));

    __syncthreads();
    if (t == 0) {
        float sum = 0.f;
        #pragma unroll
        for (int i = 0; i < NW; ++i) sum += bl[i];
        atomicAdd(out, sum);
    }
}

extern "C" void kernel_launch(void* const* d_in, const int* in_sizes, int n_in,
                              void* d_out, int out_size, void* d_ws, size_t ws_size,
                              hipStream_t stream)
{
    const float* yhat = (const float*)d_in[0];
    const float* y    = (const float*)d_in[1];
    float* out = (float*)d_out;
    const int B = in_sizes[0] / 1024;   // 32*32 per matrix

    (void)hipMemsetAsync(out, 0, sizeof(float), stream);
    const int grid = (B + NW - 1) / NW;
    hipLaunchKernelGGL(geo_loss_mfma, dim3(grid), dim3(128), 0, stream,
                       yhat, y, out, B);
}

// Round 15
// 133.296 us; speedup vs baseline: 4.0559x; 4.0559x over previous
//
#include <hip/hip_runtime.h>
#include <hip/hip_bf16.h>
#include <math.h>

#define NW 2   // waves (=samples) per 128-thread block

typedef __attribute__((ext_vector_type(8)))  short bf16x8;
typedef __attribute__((ext_vector_type(16))) float f32x16;

__device__ __forceinline__ float bperm(int srcidx, float x) {
    return __int_as_float(__builtin_amdgcn_ds_bpermute(srcidx, __float_as_int(x)));
}
// f32 -> bf16 bits, RNE (manual, bit-deterministic: probes)
__device__ __forceinline__ unsigned f2bfu(float x) {
    unsigned u = __float_as_uint(x);
    return (u + 0x7fffu + ((u >> 16) & 1u)) >> 16;
}
__device__ __forceinline__ float bf2f(unsigned hb) { return __uint_as_float(hb << 16); }
__device__ __forceinline__ unsigned short bfb(float x) {
    __hip_bfloat16 b = __float2bfloat16(x);
    unsigned short u;
    __builtin_memcpy(&u, &b, sizeof(u));
    return u;
}
__device__ __forceinline__ void split(float x, unsigned short& hb, unsigned short& lb) {
    hb = bfb(x);
    float lo = x - bf2f(hb);
    lb = bfb(lo);
}
template <int JM>
__device__ __forceinline__ bf16x8 pick(const unsigned short (&s)[8]) {
    bf16x8 r;
    #pragma unroll
    for (int j = 0; j < 8; ++j) {
        int idx = (JM == 0) ? j : (JM == 1 ? (j ^ 4) : (7 - j));
        r[j] = (short)s[idx];
    }
    return r;
}

// logm via Chebyshev of log on [1,8] (T1..T11); MFMA 32x32x16 bf16 hi/lo split;
// layout discovered by 3 one-MFMA probes (proven R10-R12, absmax 0.0).
// R14: dual-chain fusion retained from R13 but with __launch_bounds__(128,1)
// (VGPR cap 512 -> no spill; R13's (128,2) forced a 128 cap -> 1 GB scratch) and
// rws[] removed from loop-live state (only rq[4] quad bases survive init).
__global__ __launch_bounds__(128, 1)
void geo_loss_mfma(const float* __restrict__ yhat, const float* __restrict__ y,
                   float* __restrict__ out, int B)
{
    __shared__ unsigned short hA[NW][32][40], lA[NW][32][40];  // chain-1 T_k planes
    __shared__ unsigned short hB[NW][32][40], lB[NW][32][40];  // chain-2 T_k planes
    __shared__ float bl[NW];

    const int t    = threadIdx.x;
    const int w    = t >> 6;
    const int lane = t & 63;
    const int c    = lane & 31;
    const int h    = lane >> 5;

    int b = blockIdx.x * NW + w;
    const float valid = (b < B) ? 1.f : 0.f;
    if (b >= B) b = B - 1;

    const f32x16 zz = {0.f,0.f,0.f,0.f,0.f,0.f,0.f,0.f,0.f,0.f,0.f,0.f,0.f,0.f,0.f,0.f};
    float sent = 0.f;

    // ---- probe 1: relative A/B slot-labeling delta (6 hypotheses) ----
    bf16x8 pa;
    #pragma unroll
    for (int j = 0; j < 8; ++j) pa[j] = (short)f2bfu((float)(8*h + j + 1));
    int sel = -1;
    #pragma unroll
    for (int cand = 0; cand < 6; ++cand) {
        const int hfc = cand & 1, jmc = cand >> 1;
        bf16x8 pb;
        #pragma unroll
        for (int j = 0; j < 8; ++j) {
            int hh = hfc ? (1 - h) : h;
            int jj = (jmc == 0) ? j : (jmc == 1 ? (j ^ 4) : (7 - j));
            float lab = (float)(8*hh + jj + 1);
            pb[j] = (short)f2bfu(lab * lab);
        }
        f32x16 pr = __builtin_amdgcn_mfma_f32_32x32x16_bf16(pa, pb, zz, 0, 0, 0);
        if (sel < 0 && __ballot(pr[0] != 18496.f) == 0ull) sel = cand;
    }
    if (sel < 0) { sent += 1.0e10f; sel = 0; }
    const int hf = sel & 1, jm = sel >> 1;

    // ---- probe 2: C (lane,reg) -> row map (init-only; dies after setup) ----
    bf16x8 pa2, pb1;
    #pragma unroll
    for (int j = 0; j < 8; ++j) {
        pa2[j] = (short)f2bfu((float)(c + 1));
        pb1[j] = (short)f2bfu(1.f);
    }
    f32x16 r2 = __builtin_amdgcn_mfma_f32_32x32x16_bf16(pa2, pb1, zz, 0, 0, 0);
    int rws[16]; bool ok2 = true;
    #pragma unroll
    for (int i = 0; i < 16; ++i) {
        float q = r2[i] * 0.0625f;
        int ri = (int)(q + 0.5f);
        ok2 = ok2 && (fabsf(q - (float)ri) < 1e-3f) && ri >= 1 && ri <= 32;
        rws[i] = ri - 1;
    }
    if (__ballot(!ok2) != 0ull) {
        sent += 2.0e10f;
        #pragma unroll
        for (int i = 0; i < 16; ++i) rws[i] = (i & 3) + 8*(i >> 2) + 4*h;
    }

    // ---- probe 3: C lane -> col map ----
    f32x16 r3 = __builtin_amdgcn_mfma_f32_32x32x16_bf16(pb1, pa2, zz, 0, 0, 0);
    int colstar;
    {
        float q = r3[0] * 0.0625f;
        int ci = (int)(q + 0.5f);
        bool ok3 = (fabsf(q - (float)ci) < 1e-3f) && ci >= 1 && ci <= 32;
        colstar = ci - 1;
        if (__ballot(!ok3) != 0ull) { sent += 4.0e10f; colstar = c; }
    }

    // quad-contiguity; keep ONLY rq[4] live through the loop
    bool qok = true;
    int rq[4];
    #pragma unroll
    for (int q = 0; q < 4; ++q) {
        rq[q] = rws[4*q];
        qok = qok && ((rws[4*q] & 3) == 0) && (rws[4*q+1] == rws[4*q]+1)
                  && (rws[4*q+2] == rws[4*q]+2) && (rws[4*q+3] == rws[4*q]+3);
    }
    if (__ballot(!qok) != 0ull) {          // cold: sentinel + formula quads
        sent += 8.0e10f;
        #pragma unroll
        for (int q = 0; q < 4; ++q) rq[q] = 8*q + 4*h;
    }
    if (lane == 0 && sent > 0.f) atomicAdd(out, sent);

    const float INV = 0.2857142857142857f;   // 1/3.5
    const int abase = 8 * (h ^ hf);

    auto packw = [](const unsigned short (&s)[8]) {
        return make_uint4((unsigned)s[0] | ((unsigned)s[1] << 16),
                          (unsigned)s[2] | ((unsigned)s[3] << 16),
                          (unsigned)s[4] | ((unsigned)s[5] << 16),
                          (unsigned)s[6] | ((unsigned)s[7] << 16));
    };

    // ---- load + stage both samples' S; build A-frags ----
    bf16x8 A1h0, A1l0, A1h1, A1l1, A2h0, A2l0, A2h1, A2l1;
    {
        const float* Mp = yhat + ((size_t)b << 10);
        unsigned short H0[8], L0[8], H1[8], L1[8];
        const float4* p0 = reinterpret_cast<const float4*>(Mp + c*32 + abase);
        float4 q0 = p0[0], q1 = p0[1];
        float f0[8] = {q0.x,q0.y,q0.z,q0.w, q1.x,q1.y,q1.z,q1.w};
        const float4* p1 = reinterpret_cast<const float4*>(Mp + c*32 + 16 + abase);
        float4 q2 = p1[0], q3 = p1[1];
        float f1[8] = {q2.x,q2.y,q2.z,q2.w, q3.x,q3.y,q3.z,q3.w};
        #pragma unroll
        for (int m = 0; m < 8; ++m) {
            int k0 = abase + m, k1 = 16 + abase + m;
            float x0 = (f0[m] - ((k0 == c) ? 4.5f : 0.f)) * INV;
            float x1 = (f1[m] - ((k1 == c) ? 4.5f : 0.f)) * INV;
            split(x0, H0[m], L0[m]);
            split(x1, H1[m], L1[m]);
        }
        *reinterpret_cast<uint4*>(&hA[w][c][abase])      = packw(H0);
        *reinterpret_cast<uint4*>(&lA[w][c][abase])      = packw(L0);
        *reinterpret_cast<uint4*>(&hA[w][c][16 + abase]) = packw(H1);
        *reinterpret_cast<uint4*>(&lA[w][c][16 + abase]) = packw(L1);
        if (jm == 0)      { A1h0=pick<0>(H0); A1l0=pick<0>(L0); A1h1=pick<0>(H1); A1l1=pick<0>(L1); }
        else if (jm == 1) { A1h0=pick<1>(H0); A1l0=pick<1>(L0); A1h1=pick<1>(H1); A1l1=pick<1>(L1); }
        else              { A1h0=pick<2>(H0); A1l0=pick<2>(L0); A1h1=pick<2>(H1); A1l1=pick<2>(L1); }
    }
    {
        const float* Mp = y + ((size_t)b << 10);
        unsigned short H0[8], L0[8], H1[8], L1[8];
        const float4* p0 = reinterpret_cast<const float4*>(Mp + c*32 + abase);
        float4 q0 = p0[0], q1 = p0[1];
        float f0[8] = {q0.x,q0.y,q0.z,q0.w, q1.x,q1.y,q1.z,q1.w};
        const float4* p1 = reinterpret_cast<const float4*>(Mp + c*32 + 16 + abase);
        float4 q2 = p1[0], q3 = p1[1];
        float f1[8] = {q2.x,q2.y,q2.z,q2.w, q3.x,q3.y,q3.z,q3.w};
        #pragma unroll
        for (int m = 0; m < 8; ++m) {
            int k0 = abase + m, k1 = 16 + abase + m;
            float x0 = (f0[m] - ((k0 == c) ? 4.5f : 0.f)) * INV;
            float x1 = (f1[m] - ((k1 == c) ? 4.5f : 0.f)) * INV;
            split(x0, H0[m], L0[m]);
            split(x1, H1[m], L1[m]);
        }
        *reinterpret_cast<uint4*>(&hB[w][c][abase])      = packw(H0);
        *reinterpret_cast<uint4*>(&lB[w][c][abase])      = packw(L0);
        *reinterpret_cast<uint4*>(&hB[w][c][16 + abase]) = packw(H1);
        *reinterpret_cast<uint4*>(&lB[w][c][16 + abase]) = packw(L1);
        if (jm == 0)      { A2h0=pick<0>(H0); A2l0=pick<0>(L0); A2h1=pick<0>(H1); A2l1=pick<0>(L1); }
        else if (jm == 1) { A2h0=pick<1>(H0); A2l0=pick<1>(L0); A2h1=pick<1>(H1); A2l1=pick<1>(L1); }
        else              { A2h0=pick<2>(H0); A2l0=pick<2>(L0); A2h1=pick<2>(H1); A2l1=pick<2>(L1); }
    }

    // ---- init recurrence state (rws used here for the last time) ----
    float U1[16], V1[16], P1[16], U2[16], V2[16], P2[16];
    #pragma unroll
    for (int i = 0; i < 16; ++i) {
        float dg = (rws[i] == colstar) ? 1.f : 0.f;
        float tv1 = bf2f(hA[w][colstar][rws[i]]) + bf2f(lA[w][colstar][rws[i]]);
        float tv2 = bf2f(hB[w][colstar][rws[i]]) + bf2f(lB[w][colstar][rws[i]]);
        V1[i] = tv1; V2[i] = tv2; U1[i] = dg; U2[i] = dg;
        P1[i] = fmaf(0.95518452f, tv1, 1.2986135f * dg);
        P2[i] = fmaf(0.95518452f, tv2, 1.2986135f * dg);
    }

    // dual-chain Chebyshev step: two independent 6-MFMA chains interleave -> ILP
    auto STEP = [&](float coef, float (&W1)[16], float (&W2)[16], bool dostore) {
        bf16x8 B1h0 = *reinterpret_cast<const bf16x8*>(&hA[w][c][8*h]);
        bf16x8 B1l0 = *reinterpret_cast<const bf16x8*>(&lA[w][c][8*h]);
        bf16x8 B1h1 = *reinterpret_cast<const bf16x8*>(&hA[w][c][16 + 8*h]);
        bf16x8 B1l1 = *reinterpret_cast<const bf16x8*>(&lA[w][c][16 + 8*h]);
        bf16x8 B2h0 = *reinterpret_cast<const bf16x8*>(&hB[w][c][8*h]);
        bf16x8 B2l0 = *reinterpret_cast<const bf16x8*>(&lB[w][c][8*h]);
        bf16x8 B2h1 = *reinterpret_cast<const bf16x8*>(&hB[w][c][16 + 8*h]);
        bf16x8 B2l1 = *reinterpret_cast<const bf16x8*>(&lB[w][c][16 + 8*h]);
        f32x16 a1 = zz, a2 = zz;
        a1 = __builtin_amdgcn_mfma_f32_32x32x16_bf16(A1h0, B1h0, a1, 0,0,0);
        a2 = __builtin_amdgcn_mfma_f32_32x32x16_bf16(A2h0, B2h0, a2, 0,0,0);
        a1 = __builtin_amdgcn_mfma_f32_32x32x16_bf16(A1h0, B1l0, a1, 0,0,0);
        a2 = __builtin_amdgcn_mfma_f32_32x32x16_bf16(A2h0, B2l0, a2, 0,0,0);
        a1 = __builtin_amdgcn_mfma_f32_32x32x16_bf16(A1l0, B1h0, a1, 0,0,0);
        a2 = __builtin_amdgcn_mfma_f32_32x32x16_bf16(A2l0, B2h0, a2, 0,0,0);
        a1 = __builtin_amdgcn_mfma_f32_32x32x16_bf16(A1h1, B1h1, a1, 0,0,0);
        a2 = __builtin_amdgcn_mfma_f32_32x32x16_bf16(A2h1, B2h1, a2, 0,0,0);
        a1 = __builtin_amdgcn_mfma_f32_32x32x16_bf16(A1h1, B1l1, a1, 0,0,0);
        a2 = __builtin_amdgcn_mfma_f32_32x32x16_bf16(A2h1, B2l1, a2, 0,0,0);
        a1 = __builtin_amdgcn_mfma_f32_32x32x16_bf16(A1l1, B1h1, a1, 0,0,0);
        a2 = __builtin_amdgcn_mfma_f32_32x32x16_bf16(A2l1, B2h1, a2, 0,0,0);
        #pragma unroll
        for (int i = 0; i < 16; ++i) {
            float n1 = fmaf(2.f, a1[i], -W1[i]);
            float n2 = fmaf(2.f, a2[i], -W2[i]);
            W1[i] = n1; W2[i] = n2;
            P1[i] = fmaf(coef, n1, P1[i]);
            P2[i] = fmaf(coef, n2, P2[i]);
        }
        if (dostore) {
            #pragma unroll
            for (int q = 0; q < 4; ++q) {
                int r0 = rq[q];
                unsigned short h1[4], l1[4], h2[4], l2[4];
                #pragma unroll
                for (int e = 0; e < 4; ++e) {
                    split(W1[4*q+e], h1[e], l1[e]);
                    split(W2[4*q+e], h2[e], l2[e]);
                }
                *reinterpret_cast<uint2*>(&hA[w][colstar][r0]) =
                    make_uint2((unsigned)h1[0] | ((unsigned)h1[1] << 16),
                               (unsigned)h1[2] | ((unsigned)h1[3] << 16));
                *reinterpret_cast<uint2*>(&lA[w][colstar][r0]) =
                    make_uint2((unsigned)l1[0] | ((unsigned)l1[1] << 16),
                               (unsigned)l1[2] | ((unsigned)l1[3] << 16));
                *reinterpret_cast<uint2*>(&hB[w][colstar][r0]) =
                    make_uint2((unsigned)h2[0] | ((unsigned)h2[1] << 16),
                               (unsigned)h2[2] | ((unsigned)h2[3] << 16));
                *reinterpret_cast<uint2*>(&lB[w][colstar][r0]) =
                    make_uint2((unsigned)l2[0] | ((unsigned)l2[1] << 16),
                               (unsigned)l2[2] | ((unsigned)l2[3] << 16));
            }
        }
    };

    STEP(-0.22809412f, U1, U2, true);    // T2
    STEP( 0.07262391f, V1, V2, true);    // T3
    STEP(-0.02601347f, U1, U2, true);    // T4
    STEP( 0.00993906f, V1, V2, true);    // T5
    STEP(-0.00395568f, U1, U2, true);    // T6
    STEP( 0.00161931f, V1, V2, true);    // T7
    STEP(-0.00067670f, U1, U2, true);    // T8
    STEP( 0.00028728f, V1, V2, true);    // T9
    STEP(-0.00012348f, U1, U2, true);    // T10
    STEP( 0.00005361f, V1, V2, false);   // T11 (T12 term dropped: adds <=2.4e-5)

    float s = 0.f;
    #pragma unroll
    for (int i = 0; i < 16; ++i) { float d = P1[i] - P2[i]; s = fmaf(d, d, s); }
    #pragma unroll
    for (int m = 32; m >= 1; m >>= 1)
        s += bperm((lane ^ m) << 2, s);
    if (lane == 0) bl[w] = valid * sqrtf(fmaxf(s, 0.f));

    __syncthreads();
    if (t == 0) {
        float sum = 0.f;
        #pragma unroll
        for (int i = 0; i < NW; ++i) sum += bl[i];
        atomicAdd(out, sum);
    }
}

extern "C" void kernel_launch(void* const* d_in, const int* in_sizes, int n_in,
                              void* d_out, int out_size, void* d_ws, size_t ws_size,
                              hipStream_t stream)
{
    const float* yhat = (const float*)d_in[0];
    const float* y    = (const float*)d_in[1];
    float* out = (float*)d_out;
    const int B = in_sizes[0] / 1024;   // 32*32 per matrix

    (void)hipMemsetAsync(out, 0, sizeof(float), stream);
    const int grid = (B + NW - 1) / NW;
    hipLaunchKernelGGL(geo_loss_mfma, dim3(grid), dim3(128), 0, stream,
                       yhat, y, out, B);
}